// Round 9
// baseline (1065.065 us; speedup 1.0000x reference)
//
#include <hip/hip_runtime.h>
#include <hip/hip_bf16.h>

// ---------------------------------------------------------------------------
// QuadraticGNN: 3x ResGatedGraphConv (ReLU gate, LeakyReLU 0.01, linear Wl)
//               -> global mean pool (32 graphs) -> 5-layer MLP with BN.
// Round 8:
//   - GEMM K-loop restructured m97-style: A pre-converted to bf16 hi/lo by
//     its producer (aconv for x, Wl epilogue for h, edge gather for leaky(S)),
//     staged via global_load_lds width=16. No VALU conversion in the loop.
//   - XOR-swizzled k-chunk tile layout (chunk ^= (row>>1)&3): unpadded LDS
//     (global_load_lds requires it) with conflict-free ds_read_b128.
//   - Wl2 merged to one K=128 dispatch (no accum round-trip). 12 -> 9 GEMMs.
//   - Arithmetic identical to round 7 (same hi/lo split, same leaky order).
// ---------------------------------------------------------------------------

#define GN_N 100000
#define GN_E 300000
#define GN_G 32
#define GN_NP 100096   // 128-row padded for tile staging overrun

typedef __attribute__((ext_vector_type(8))) short short8;
typedef __attribute__((ext_vector_type(4))) float floatx4;

__device__ inline ushort f2bf_rne(float f) {
    unsigned u = __float_as_uint(f);
    unsigned r = u + 0x7fffu + ((u >> 16) & 1u);
    return (ushort)(r >> 16);
}
__device__ inline float bf2f(ushort h) { return __uint_as_float(((unsigned)h) << 16); }

// swizzled position of k within a row: 8-wide chunks XOR'd by (row>>1)&3
__device__ inline int swz(int k, int row) {
    return (k & ~31) + ((((k >> 3) & 3) ^ ((row >> 1) & 3)) << 3) + (k & 7);
}

__device__ inline void gll16(const void* g, void* l) {
    __builtin_amdgcn_global_load_lds(
        (const __attribute__((address_space(1))) void*)g,
        (__attribute__((address_space(3))) void*)l, 16, 0, 0);
}

// W-array layout (ushort offsets), k-major [col][K] per segment, swizzled.
#define WOFF_L2   32768
#define WOFF_L3   65536
#define WOFF_WL1  196608
#define WOFF_WL2  200704
#define W_TOTAL   217088

struct WSrc {
    const float* Wg[3][4];
    const float* Wl[2];
    const float* bg[3][4];
};

__global__ void wconv(WSrc S, ushort* __restrict__ hi, ushort* __restrict__ lo,
                      float* __restrict__ biascat)
{
    int id = blockIdx.x * 256 + threadIdx.x;
    if (id < 196608) {
        int l, base, ci, co;
        if (id < 32768)      { l = 0; base = 0;        ci = 128; co = 64;  }
        else if (id < 65536) { l = 1; base = WOFF_L2;  ci = 64;  co = 128; }
        else                 { l = 2; base = WOFF_L3;  ci = 128; co = 256; }
        int r  = id - base;
        int g  = r / (co * ci);
        int r2 = r - g * co * ci;
        int c  = r2 / ci;
        int k  = r2 - c * ci;
        float v = S.Wg[l][g][k * co + c];
        int ch  = c >> 6;
        int colIdx = (g << 6) + (c & 63);
        int dst = base + ch * (256 * ci) + colIdx * ci + swz(k, colIdx);
        ushort h = f2bf_rne(v);
        hi[dst] = h; lo[dst] = f2bf_rne(v - bf2f(h));
    } else if (id < 196608 + 4096) {
        int r = id - 196608;
        int c = r >> 6, k = r & 63;
        float v = S.Wl[0][k * 64 + c];
        int dst = WOFF_WL1 + c * 64 + swz(k, c);
        ushort h = f2bf_rne(v);
        hi[dst] = h; lo[dst] = f2bf_rne(v - bf2f(h));
    } else if (id < W_TOTAL) {
        int r = id - WOFF_WL2;
        int c = r >> 7, k2 = r & 127;
        float v = S.Wl[1][k2 * 128 + c];
        int dst = WOFF_WL2 + c * 128 + swz(k2, c);
        ushort h = f2bf_rne(v);
        hi[dst] = h; lo[dst] = f2bf_rne(v - bf2f(h));
    } else if (id < W_TOTAL + 1792) {
        int i = id - W_TOTAL;
        int chunk = i >> 8, c = i & 255;
        int g = c >> 6, cc = c & 63;
        const int ltab[7] = {0, 1, 1, 2, 2, 2, 2};
        const int ctab[7] = {0, 0, 64, 0, 64, 128, 192};
        biascat[i] = S.bg[ltab[chunk]][g][ctab[chunk] + cc];
    }
}

// x (fp32 [N][128]) -> swizzled bf16 hi/lo [N][128]
__global__ void aconv(const float* __restrict__ A,
                      ushort* __restrict__ Oh, ushort* __restrict__ Ol)
{
    int id = blockIdx.x * 256 + threadIdx.x;
    if (id >= GN_N * 16) return;
    int r = id >> 4, cchunk = id & 15;
    const float* src = A + (size_t)r * 128 + cchunk * 8;
    int kpos = (cchunk >> 2) * 32 + (((cchunk & 3) ^ ((r >> 1) & 3)) << 3);
    short8 h, l;
    #pragma unroll
    for (int j = 0; j < 8; ++j) {
        float v = src[j];
        ushort hh = f2bf_rne(v);
        h[j] = (short)hh; l[j] = (short)f2bf_rne(v - bf2f(hh));
    }
    *(short8*)&Oh[(size_t)r * 128 + kpos] = h;
    *(short8*)&Ol[(size_t)r * 128 + kpos] = l;
}

// C = A @ B + bias. A: bf16 hi/lo [row][K] swizzled. B: [col][K] swizzled (ws).
// OUTBF=0: fp32 store to C (ldc). OUTBF=1: bf16 hi/lo swizzled store (ldo).
template<int BC, int OUTBF>
__global__ __launch_bounds__(256) void gemm_gll(
    const ushort* __restrict__ Ah, const ushort* __restrict__ Al,
    const ushort* __restrict__ Bh, const ushort* __restrict__ Bl,
    const float* __restrict__ bias,
    float* __restrict__ C, int ldc,
    ushort* __restrict__ Oh, ushort* __restrict__ Ol, int ldo,
    int K)
{
    constexpr int RT  = (BC == 128) ? 4 : 2;
    constexpr int TB  = (BC == 128) ? 8 : 4;     // B instrs per component
    constexpr int TOT = 16 + 2 * TB;             // total gll instrs per tile
    constexpr int PERW = TOT / 4;
    alignas(16) __shared__ ushort sAh[128 * 32], sAl[128 * 32];
    alignas(16) __shared__ ushort sBh[BC * 32],  sBl[BC * 32];

    const int tid  = threadIdx.x;
    const int w    = tid >> 6, lane = tid & 63;
    const int m    = lane & 15, quad = lane >> 4;
    const int row0 = blockIdx.x * 128;
    const int col0 = blockIdx.y * BC;
    const int wr   = (BC == 128) ? (w >> 1) * 64 : w * 32;
    const int wc   = (BC == 128) ? (w & 1) * 64 : 0;
    const int r16  = lane >> 2, c4 = lane & 3;

    floatx4 acc[RT][4];
    #pragma unroll
    for (int i = 0; i < RT; ++i)
        #pragma unroll
        for (int j = 0; j < 4; ++j) acc[i][j] = (floatx4){0.f, 0.f, 0.f, 0.f};

    for (int kt = 0; kt < (K >> 5); ++kt) {
        const int kb = kt * 32;
        #pragma unroll
        for (int i = 0; i < PERW; ++i) {
            int slot = w * PERW + i;
            const ushort* g; ushort* l;
            if (slot < 8) {
                int rl = slot * 16 + r16;
                g = Ah + (size_t)(row0 + rl) * K + kb + c4 * 8;
                l = sAh + slot * 512;
            } else if (slot < 16) {
                int rl = (slot - 8) * 16 + r16;
                g = Al + (size_t)(row0 + rl) * K + kb + c4 * 8;
                l = sAl + (slot - 8) * 512;
            } else if (slot < 16 + TB) {
                int rl = (slot - 16) * 16 + r16;
                g = Bh + (size_t)(col0 + rl) * K + kb + c4 * 8;
                l = sBh + (slot - 16) * 512;
            } else {
                int rl = (slot - 16 - TB) * 16 + r16;
                g = Bl + (size_t)(col0 + rl) * K + kb + c4 * 8;
                l = sBl + (slot - 16 - TB) * 512;
            }
            gll16(g, l);
        }
        __syncthreads();

        short8 bhf[4], blf[4];
        #pragma unroll
        for (int ct = 0; ct < 4; ++ct) {
            int rb_ = wc + ct * 16 + m;
            int off = rb_ * 32 + ((quad ^ ((rb_ >> 1) & 3)) << 3);
            bhf[ct] = *(const short8*)&sBh[off];
            blf[ct] = *(const short8*)&sBl[off];
        }
        #pragma unroll
        for (int rt = 0; rt < RT; ++rt) {
            int ra = wr + rt * 16 + m;
            int off = ra * 32 + ((quad ^ ((ra >> 1) & 3)) << 3);
            short8 ahf = *(const short8*)&sAh[off];
            short8 alf = *(const short8*)&sAl[off];
            #pragma unroll
            for (int ct = 0; ct < 4; ++ct) {
                acc[rt][ct] = __builtin_amdgcn_mfma_f32_16x16x32_bf16(ahf, bhf[ct], acc[rt][ct], 0, 0, 0);
                acc[rt][ct] = __builtin_amdgcn_mfma_f32_16x16x32_bf16(ahf, blf[ct], acc[rt][ct], 0, 0, 0);
                acc[rt][ct] = __builtin_amdgcn_mfma_f32_16x16x32_bf16(alf, bhf[ct], acc[rt][ct], 0, 0, 0);
            }
        }
        __syncthreads();
    }

    #pragma unroll
    for (int rt = 0; rt < RT; ++rt) {
        #pragma unroll
        for (int ct = 0; ct < 4; ++ct) {
            int ocol = col0 + wc + ct * 16 + m;
            #pragma unroll
            for (int reg = 0; reg < 4; ++reg) {
                int orow = row0 + wr + rt * 16 + quad * 4 + reg;
                if (orow < GN_N) {
                    float v = acc[rt][ct][reg] + bias[ocol];
                    if (OUTBF) {
                        ushort h = f2bf_rne(v);
                        ushort lo = f2bf_rne(v - bf2f(h));
                        int kpos = swz(ocol, orow);
                        Oh[(size_t)orow * ldo + kpos] = h;
                        Ol[(size_t)orow * ldo + kpos] = lo;
                    } else {
                        C[(size_t)orow * ldc + ocol] = v;
                    }
                }
            }
        }
    }
}

// ---------------- CSR build ----------------
__global__ void zero_int(int* p, int n)
{
    int i = blockIdx.x * 256 + threadIdx.x;
    if (i < n) p[i] = 0;
}

__global__ void hist_kernel(const int* __restrict__ dst, int* __restrict__ deg)
{
    int e = blockIdx.x * 256 + threadIdx.x;
    if (e < GN_E) atomicAdd(&deg[dst[e]], 1);
}

__global__ void scan1(const int* __restrict__ deg, int* __restrict__ rp, int* __restrict__ bsums)
{
    __shared__ int s[256];
    int b = blockIdx.x, t = threadIdx.x;
    int i = b * 256 + t;
    int v = (i < GN_N) ? deg[i] : 0;
    s[t] = v;
    __syncthreads();
    for (int off = 1; off < 256; off <<= 1) {
        int x = (t >= off) ? s[t - off] : 0;
        __syncthreads();
        s[t] += x;
        __syncthreads();
    }
    if (i < GN_N) rp[i] = s[t] - v;
    if (t == 255) bsums[b] = s[255];
}

__global__ __launch_bounds__(512) void scan2(int* bsums, int nb)
{
    __shared__ int s[512];
    int t = threadIdx.x;
    int v = (t < nb) ? bsums[t] : 0;
    s[t] = v;
    __syncthreads();
    for (int off = 1; off < 512; off <<= 1) {
        int x = (t >= off) ? s[t - off] : 0;
        __syncthreads();
        s[t] += x;
        __syncthreads();
    }
    if (t < nb) bsums[t] = s[t] - v;
}

__global__ void scan3(const int* __restrict__ bsums, int* __restrict__ rp, int* __restrict__ cursor)
{
    int b = blockIdx.x, t = threadIdx.x;
    int i = b * 256 + t;
    if (i < GN_N) {
        int v = rp[i] + bsums[b];
        rp[i] = v; cursor[i] = v;
    }
    if (i == 0) rp[GN_N] = GN_E;
}

__global__ void scatter_kernel(
    const int* __restrict__ src, const int* __restrict__ dst,
    int* __restrict__ cursor, int* __restrict__ elist)
{
    int e = blockIdx.x * 256 + threadIdx.x;
    if (e >= GN_E) return;
    int d = dst[e];
    int pos = atomicAdd(&cursor[d], 1);
    elist[pos] = src[e];
}

__global__ void bounds_kernel(const int* __restrict__ batch, int* __restrict__ se)
{
    int i = blockIdx.x * 256 + threadIdx.x;
    if (i >= GN_N) return;
    int g = batch[i];
    if (i == 0 || batch[i - 1] != g) se[g] = i;
    if (i == GN_N - 1 || batch[i + 1] != g) se[32 + g] = i + 1;
}

__global__ void cnt_kernel(const int* __restrict__ se, float* __restrict__ cnt)
{
    int g = threadIdx.x;
    if (g < GN_G) cnt[g] = (float)(se[32 + g] - se[g]);
}

// l1/l2 gather: agg = S + sum relu(K+Q)*V, then leaky, then store bf16 hi/lo
// in swizzled [node][lds_] layout at k-offset c0out. 4 nodes/wave.
__global__ __launch_bounds__(256) void edge_gather_s(
    const float* __restrict__ G,
    const int* __restrict__ row_ptr, const int* __restrict__ elist,
    ushort* __restrict__ Sh, ushort* __restrict__ Sl, int lds_, int c0out)
{
    int w = threadIdx.x >> 6, c = threadIdx.x & 63;
    int n0 = blockIdx.x * 16 + w * 4;

    float k[4], acc[4];
    int beg[4], end[4];
    #pragma unroll
    for (int j = 0; j < 4; ++j) {
        int node = n0 + j;
        bool ok = node < GN_N;
        int nd = ok ? node : 0;
        beg[j] = row_ptr[nd];
        end[j] = ok ? row_ptr[nd + 1] : beg[j];
        k[j]   = G[(size_t)nd * 256 + c];
        acc[j] = G[(size_t)nd * 256 + 192 + c];
    }
    int s[16];
    #pragma unroll
    for (int j = 0; j < 4; ++j) {
        #pragma unroll
        for (int e = 0; e < 4; ++e) {
            int idx = beg[j] + e;
            s[j * 4 + e] = elist[idx < end[j] ? idx : 0];
        }
    }
    float q[16], v[16];
    #pragma unroll
    for (int je = 0; je < 16; ++je) {
        q[je] = G[(size_t)s[je] * 256 + 64 + c];
        v[je] = G[(size_t)s[je] * 256 + 128 + c];
    }
    #pragma unroll
    for (int j = 0; j < 4; ++j) {
        #pragma unroll
        for (int e = 0; e < 4; ++e) {
            if (beg[j] + e < end[j]) {
                float gt = k[j] + q[j * 4 + e];
                if (gt > 0.f) acc[j] += gt * v[j * 4 + e];
            }
        }
    }
    #pragma unroll
    for (int j = 0; j < 4; ++j) {
        for (int i = beg[j] + 4; i < end[j]; ++i) {
            int ss = elist[i];
            float qq = G[(size_t)ss * 256 + 64 + c];
            float vv = G[(size_t)ss * 256 + 128 + c];
            float gt = k[j] + qq;
            if (gt > 0.f) acc[j] += gt * vv;
        }
    }
    int k2 = c0out + c;
    #pragma unroll
    for (int j = 0; j < 4; ++j) {
        int node = n0 + j;
        if (node < GN_N) {
            float a = acc[j];
            a = a > 0.f ? a : 0.01f * a;   // leaky (Wl input)
            int kpos = swz(k2, node);
            ushort h = f2bf_rne(a);
            Sh[(size_t)node * lds_ + kpos] = h;
            Sl[(size_t)node * lds_ + kpos] = f2bf_rne(a - bf2f(h));
        }
    }
}

// Layer-3: gather + leaky + 16-node LDS reduce + run-length atomics into sums.
__global__ __launch_bounds__(256) void edge_gather_pool(
    const float* __restrict__ G,
    const int* __restrict__ row_ptr, const int* __restrict__ elist,
    const int* __restrict__ batch,
    float* __restrict__ sums, int c0)
{
    __shared__ float red[16][64];
    __shared__ int gid[16];
    int w = threadIdx.x >> 6, c = threadIdx.x & 63;
    int n0 = blockIdx.x * 16 + w * 4;

    float k[4], acc[4];
    int beg[4], end[4];
    #pragma unroll
    for (int j = 0; j < 4; ++j) {
        int node = n0 + j;
        bool ok = node < GN_N;
        int nd = ok ? node : 0;
        beg[j] = row_ptr[nd];
        end[j] = ok ? row_ptr[nd + 1] : beg[j];
        k[j]   = G[(size_t)nd * 256 + c];
        acc[j] = ok ? G[(size_t)nd * 256 + 192 + c] : 0.f;
    }
    int s[16];
    #pragma unroll
    for (int j = 0; j < 4; ++j) {
        #pragma unroll
        for (int e = 0; e < 4; ++e) {
            int idx = beg[j] + e;
            s[j * 4 + e] = elist[idx < end[j] ? idx : 0];
        }
    }
    float q[16], v[16];
    #pragma unroll
    for (int je = 0; je < 16; ++je) {
        q[je] = G[(size_t)s[je] * 256 + 64 + c];
        v[je] = G[(size_t)s[je] * 256 + 128 + c];
    }
    #pragma unroll
    for (int j = 0; j < 4; ++j) {
        #pragma unroll
        for (int e = 0; e < 4; ++e) {
            if (beg[j] + e < end[j]) {
                float gt = k[j] + q[j * 4 + e];
                if (gt > 0.f) acc[j] += gt * v[j * 4 + e];
            }
        }
    }
    #pragma unroll
    for (int j = 0; j < 4; ++j) {
        for (int i = beg[j] + 4; i < end[j]; ++i) {
            int ss = elist[i];
            float qq = G[(size_t)ss * 256 + 64 + c];
            float vv = G[(size_t)ss * 256 + 128 + c];
            float gt = k[j] + qq;
            if (gt > 0.f) acc[j] += gt * vv;
        }
    }
    #pragma unroll
    for (int j = 0; j < 4; ++j) {
        float a = acc[j];
        red[w * 4 + j][c] = a > 0.f ? a : 0.01f * a;
    }
    if (c < 4) {
        int node = n0 + c;
        gid[w * 4 + c] = (node < GN_N) ? batch[node] : -1;
    }
    __syncthreads();
    if (w == 0) {
        int i = 0;
        while (i < 16) {
            int gg = gid[i];
            float sum = 0.f;
            int j = i;
            while (j < 16 && gid[j] == gg) { sum += red[j][c]; ++j; }
            if (gg >= 0) atomicAdd(&sums[gg * 256 + c0 + c], sum);
            i = j;
        }
    }
}

__global__ void zero_sums(float* sums)
{
    int i = blockIdx.x * 256 + threadIdx.x;
    if (i < GN_G * 256) sums[i] = 0.0f;
}

// One block per graph: Pl = sums[g]/cnt[g]; Pg = Pl @ Wl3 + bl3; BN-MLP chain.
__global__ __launch_bounds__(256) void mlp_kernel(
    const float* __restrict__ sums, const float* __restrict__ cnt,
    const float* __restrict__ Wl3, const float* __restrict__ bl3,
    const float* __restrict__ W1, const float* __restrict__ b1,
    const float* __restrict__ Wh, const float* __restrict__ bh,
    const float* __restrict__ Wo, const float* __restrict__ bo,
    const float* __restrict__ gamma, const float* __restrict__ beta,
    const float* __restrict__ mean, const float* __restrict__ var,
    float* __restrict__ out)
{
    __shared__ float sp[256];
    __shared__ float pg[256];
    __shared__ float h0[64], h1[64];
    const int g = blockIdx.x;
    const int t = threadIdx.x;
    const float inv = 1.0f / fmaxf(cnt[g], 1.0f);

    sp[t] = sums[g * 256 + t] * inv;
    __syncthreads();

    {
        float a0 = 0.f, a1 = 0.f, a2 = 0.f, a3 = 0.f;
        #pragma unroll 4
        for (int k = 0; k < 256; k += 4) {
            a0 += sp[k + 0] * Wl3[(k + 0) * 256 + t];
            a1 += sp[k + 1] * Wl3[(k + 1) * 256 + t];
            a2 += sp[k + 2] * Wl3[(k + 2) * 256 + t];
            a3 += sp[k + 3] * Wl3[(k + 3) * 256 + t];
        }
        pg[t] = bl3[t] + ((a0 + a1) + (a2 + a3));
    }
    __syncthreads();

    if (t < 64) {
        float a0 = 0.f, a1 = 0.f, a2 = 0.f, a3 = 0.f;
        #pragma unroll 4
        for (int k = 0; k < 256; k += 4) {
            a0 += pg[k + 0] * W1[(k + 0) * 64 + t];
            a1 += pg[k + 1] * W1[(k + 1) * 64 + t];
            a2 += pg[k + 2] * W1[(k + 2) * 64 + t];
            a3 += pg[k + 3] * W1[(k + 3) * 64 + t];
        }
        float acc = b1[t] + ((a0 + a1) + (a2 + a3));
        float sc = gamma[t] * rsqrtf(var[t] + 1e-5f);
        acc = (acc - mean[t]) * sc + beta[t];
        h0[t] = fmaxf(acc, 0.0f);
    }
    __syncthreads();

    for (int L = 0; L < 3; ++L) {
        const float* W  = Wh + L * 64 * 64;
        const float* hin  = (L & 1) ? h1 : h0;
        float*       hout = (L & 1) ? h0 : h1;
        if (t < 64) {
            const float* ga = gamma + (L + 1) * 64;
            const float* be = beta  + (L + 1) * 64;
            const float* me = mean  + (L + 1) * 64;
            const float* va = var   + (L + 1) * 64;
            float a0 = 0.f, a1 = 0.f, a2 = 0.f, a3 = 0.f;
            #pragma unroll 4
            for (int k = 0; k < 64; k += 4) {
                a0 += hin[k + 0] * W[(k + 0) * 64 + t];
                a1 += hin[k + 1] * W[(k + 1) * 64 + t];
                a2 += hin[k + 2] * W[(k + 2) * 64 + t];
                a3 += hin[k + 3] * W[(k + 3) * 64 + t];
            }
            float acc = (bh + L * 64)[t] + ((a0 + a1) + (a2 + a3));
            float sc = ga[t] * rsqrtf(va[t] + 1e-5f);
            acc = (acc - me[t]) * sc + be[t];
            hout[t] = fmaxf(acc, 0.0f);
        }
        __syncthreads();
    }

    if (t < 8) {
        const float* hf = h1;
        float acc = bo[t];
        for (int k = 0; k < 64; ++k) acc += hf[k] * Wo[k * 8 + t];
        out[g * 8 + t] = acc;
    }
}

extern "C" void kernel_launch(void* const* d_in, const int* in_sizes, int n_in,
                              void* d_out, int out_size, void* d_ws, size_t ws_size,
                              hipStream_t stream)
{
    const int N = GN_N, E = GN_E, NP = GN_NP;
    const float* x          = (const float*)d_in[0];
    const int*   edge_index = (const int*)d_in[1];
    const int*   batch      = (const int*)d_in[2];
    const int*   src = edge_index;
    const int*   dst = edge_index + E;
    auto F = [&](int i) { return (const float*)d_in[i]; };

    // ---- workspace layout ----
    float* ws    = (float*)d_ws;
    float* G     = ws;                          // N x 256 fp32 [K|Q|V|S]
    float* sums  = G + (size_t)N * 256;         // 32 x 256
    float* cnt   = sums + GN_G * 256;           // 32
    float* bcat  = cnt + GN_G;                  // 7 x 256
    ushort* Whi  = (ushort*)(bcat + 1792);
    ushort* Wlo  = Whi + W_TOTAL;
    ushort* bAh  = Wlo + W_TOTAL;               // NP x 128 (XA / SA reuse)
    ushort* bAl  = bAh + (size_t)NP * 128;
    ushort* HAh  = bAl + (size_t)NP * 128;      // NP x 64
    ushort* HAl  = HAh + (size_t)NP * 64;
    ushort* HBh  = HAl + (size_t)NP * 64;       // NP x 128
    ushort* HBl  = HBh + (size_t)NP * 128;
    int* deg     = (int*)(HBl + (size_t)NP * 128);
    int* cursor  = deg + N;
    int* row_ptr = cursor + N;                  // N+1
    int* elist   = row_ptr + (N + 1);           // E
    int* bsums   = elist + E;                   // 512
    int* se      = bsums + 512;                 // 64

    size_t need = (size_t)((char*)(se + 64) - (char*)ws);
    if (ws_size < need) return;

    // ---- CSR build + graph bounds ----
    const int eb = (E + 255) / 256;
    const int nb = (N + 255) / 256;
    zero_int<<<nb, 256, 0, stream>>>(deg, N);
    zero_int<<<1, 256, 0, stream>>>(se, 64);
    hist_kernel<<<eb, 256, 0, stream>>>(dst, deg);
    scan1<<<nb, 256, 0, stream>>>(deg, row_ptr, bsums);
    scan2<<<1, 512, 0, stream>>>(bsums, nb);
    scan3<<<nb, 256, 0, stream>>>(bsums, row_ptr, cursor);
    scatter_kernel<<<eb, 256, 0, stream>>>(src, dst, cursor, elist);
    bounds_kernel<<<nb, 256, 0, stream>>>(batch, se);
    cnt_kernel<<<1, 64, 0, stream>>>(se, cnt);

    // ---- weight + input pre-conversion ----
    WSrc S;
    for (int l = 0; l < 3; ++l) {
        int base = 3 + l * 10;
        for (int g = 0; g < 4; ++g) S.Wg[l][g] = F(base + g);
        for (int g = 0; g < 4; ++g) S.bg[l][g] = F(base + 4 + g);
    }
    S.Wl[0] = F(11); S.Wl[1] = F(21);
    wconv<<<(W_TOTAL + 1792 + 255) / 256, 256, 0, stream>>>(S, Whi, Wlo, bcat);
    aconv<<<(N * 16 + 255) / 256, 256, 0, stream>>>(x, bAh, bAl);

    zero_sums<<<(GN_G * 256 + 255) / 256, 256, 0, stream>>>(sums);

    const int rb = (N + 127) / 128;
    const int gatherBlocks = (N + 15) / 16;

    // ---- layer 1 ----
    gemm_gll<128, 0><<<dim3(rb, 2), 256, 0, stream>>>(
        bAh, bAl, Whi, Wlo, bcat, G, 256, nullptr, nullptr, 0, 128);
    edge_gather_s<<<gatherBlocks, 256, 0, stream>>>(
        G, row_ptr, elist, bAh, bAl, 64, 0);
    gemm_gll<64, 1><<<dim3(rb, 1), 256, 0, stream>>>(
        bAh, bAl, Whi + WOFF_WL1, Wlo + WOFF_WL1, F(12),
        nullptr, 0, HAh, HAl, 64, 64);

    // ---- layer 2 (2 chunks) ----
    for (int ch = 0; ch < 2; ++ch) {
        size_t go = WOFF_L2 + (size_t)ch * 16384;
        gemm_gll<128, 0><<<dim3(rb, 2), 256, 0, stream>>>(
            HAh, HAl, Whi + go, Wlo + go, bcat + (1 + ch) * 256,
            G, 256, nullptr, nullptr, 0, 64);
        edge_gather_s<<<gatherBlocks, 256, 0, stream>>>(
            G, row_ptr, elist, bAh, bAl, 128, ch * 64);
    }
    gemm_gll<128, 1><<<dim3(rb, 1), 256, 0, stream>>>(
        bAh, bAl, Whi + WOFF_WL2, Wlo + WOFF_WL2, F(22),
        nullptr, 0, HBh, HBl, 128, 128);

    // ---- layer 3 (4 chunks, fused pool) ----
    for (int ch = 0; ch < 4; ++ch) {
        size_t go = WOFF_L3 + (size_t)ch * 32768;
        gemm_gll<128, 0><<<dim3(rb, 2), 256, 0, stream>>>(
            HBh, HBl, Whi + go, Wlo + go, bcat + (3 + ch) * 256,
            G, 256, nullptr, nullptr, 0, 128);
        edge_gather_pool<<<gatherBlocks, 256, 0, stream>>>(
            G, row_ptr, elist, batch, sums, ch * 64);
    }

    mlp_kernel<<<GN_G, 256, 0, stream>>>(sums, cnt, F(31), F(32),
                                         F(33), F(34), F(35), F(36), F(37), F(38),
                                         F(39), F(40), F(41), F(42),
                                         (float*)d_out);
}